// Round 9
// baseline (312.510 us; speedup 1.0000x reference)
//
#include <hip/hip_runtime.h>

#define DD 256   // feature dim
#define N1 512
#define N2 512
#define BB 4

// Packed fp32: gfx950 (gfx90a+) PackedFP32Ops; the compiler selects
// v_pk_{add,mul,fma}_f32 from <2 x float> vector IR.
typedef float f2 __attribute__((ext_vector_type(2)));

// ---------------------------------------------------------------------------
// Kernel 1: projection GEMMs. R2 version verbatim: 32x64 tile / 256 threads /
// 2x4 register blocking (packed), K-chunks of 32, register-prefetch double
// buffering, 512 blocks = 2/CU. proj is ~10 us; R3 proved its internal
// structure doesn't move the total. Leave it alone.
// ---------------------------------------------------------------------------
__global__ __launch_bounds__(256) void proj_kernel(
    const float* __restrict__ x, const float* __restrict__ y,
    const float* __restrict__ W1, const float* __restrict__ b1,
    float* __restrict__ xp, float* __restrict__ yp)
{
    const int which = blockIdx.z;
    const float* __restrict__ A  = which ? y : x;
    const float* __restrict__ Bw = W1 + which * DD * DD;
    float* __restrict__ outp = which ? yp : xp;

    __shared__ float As[32 * 36];   // As[k][m] (transposed), stride 36
    __shared__ float Bs[32 * 68];   // Bs[k][n], stride 68

    const int tid = threadIdx.x;
    const int tx = tid & 15, ty = tid >> 4;
    const int mBase = blockIdx.x * 32;
    const int nBase = blockIdx.y * 64;

    const float4* A4 = (const float4*)A;
    const float4* B4 = (const float4*)Bw;

    const int ar = tid >> 3;       // 0..31  A row (m)
    const int ac = tid & 7;        // 0..7   A float4 col (k/4)
    const int br = tid >> 4;       // 0..15  B k-row (and +16)
    const int bc = tid & 15;       // 0..15  B float4 col (n/4)

    float4 pa, pb0, pb1;
    pa  = A4[(mBase + ar) * 64 + 0 * 8 + ac];
    pb0 = B4[(0 * 32 + br) * 64 + (nBase >> 2) + bc];
    pb1 = B4[(0 * 32 + br + 16) * 64 + (nBase >> 2) + bc];

    // acc[i] split into lo/hi f2 halves of the 4-wide n block -> v_pk_fma
    f2 accl[2] = {}, acch[2] = {};

    for (int kc = 0; kc < 8; ++kc) {
        __syncthreads();
        {
            float av[4] = {pa.x, pa.y, pa.z, pa.w};
            #pragma unroll
            for (int q = 0; q < 4; ++q) As[(ac * 4 + q) * 36 + ar] = av[q];
            *(float4*)&Bs[br * 68 + bc * 4] = pb0;
            *(float4*)&Bs[(br + 16) * 68 + bc * 4] = pb1;
        }
        __syncthreads();
        if (kc < 7) {
            pa  = A4[(mBase + ar) * 64 + (kc + 1) * 8 + ac];
            pb0 = B4[((kc + 1) * 32 + br) * 64 + (nBase >> 2) + bc];
            pb1 = B4[((kc + 1) * 32 + br + 16) * 64 + (nBase >> 2) + bc];
        }
        #pragma unroll
        for (int k = 0; k < 32; ++k) {
            f2 a = *(const f2*)&As[k * 36 + ty * 2];
            float4 b = *(const float4*)&Bs[k * 68 + tx * 4];
            f2 blo = {b.x, b.y};
            f2 bhi = {b.z, b.w};
            f2 a0 = {a.x, a.x};     // splat -> op_sel, free in VOP3P
            f2 a1 = {a.y, a.y};
            accl[0] = __builtin_elementwise_fma(a0, blo, accl[0]);
            acch[0] = __builtin_elementwise_fma(a0, bhi, acch[0]);
            accl[1] = __builtin_elementwise_fma(a1, blo, accl[1]);
            acch[1] = __builtin_elementwise_fma(a1, bhi, acch[1]);
        }
    }

    float4 bias = make_float4(0.f, 0.f, 0.f, 0.f);
    if (which == 0) bias = *((const float4*)b1 + (nBase >> 2) + tx);
    #pragma unroll
    for (int i = 0; i < 2; ++i) {
        float4 o;
        o.x = accl[i].x + bias.x;
        o.y = accl[i].y + bias.y;
        o.z = acch[i].x + bias.z;
        o.w = acch[i].y + bias.w;
        ((float4*)outp)[(mBase + ty * 2 + i) * (DD / 4) + (nBase >> 2) + tx] = o;
    }
}

// ---------------------------------------------------------------------------
// Kernel 2: o[b,n,m] = sum_d gelu(xp[b,n,d] + yp[b,m,d]) * W2[d] + b2
// R8 kernel (61 us) + R9 change: LDS DOUBLE-BUFFER -> one barrier per 64-d
// chunk instead of two (8 -> 4 barriers/block). Clean A/B on dbuf itself:
// R1 bundled dbuf with a by-ref gelu helper and hit a scratch disaster
// (VGPR 64, FETCH 416 MB); gelu is now straight-line, so if the signature
// reappears dbuf is the cause and gets reverted permanently. LDS `xs[cur]`
// with runtime cur is memory addressing, not a register array (rule #20 ok).
//
// Gelu: trans-free deg-13 odd Chebyshev erf poly (R8, proven: absmax
// 0.00390625 identical). The 0.5 is now applied ONCE in the epilogue
// (0.5*sum) instead of pre-scaling W2 per c4 (saves 4 VALU/c4/thread).
// Ledger after R8: ~26 us VALU-issue floor, ~30 us LDS-pipe, ~22 us idle
// (VALUBusy 64%, 8 barriers). This attacks the idle slice.
// ---------------------------------------------------------------------------
#define GC1  0.79687960f
#define GC3  (-0.13053245f)
#define GC5  0.018104800f
#define GC7  (-0.0017319756f)
#define GC9  1.05671e-4f
#define GC11 (-3.64829e-6f)
#define GC13 5.37117e-8f

__global__ __launch_bounds__(256, 4) void cross_kernel(
    const float* __restrict__ xp, const float* __restrict__ yp,
    const float* __restrict__ W2, const float* __restrict__ b2,
    float* __restrict__ o)
{
    __shared__ float xs[2][32 * 68];   // n rows of xp chunk, double-buffered
    __shared__ float ys[2][16 * 68];   // m rows of yp chunk, double-buffered

    const int tid   = threadIdx.x;
    const int b     = blockIdx.z;
    const int mBase = blockIdx.x * 16;
    const int nBase = blockIdx.y * 32;
    const int tx = tid & 15;       // m col (single)
    const int ty = tid >> 4;       // n rows ty, ty+16

    const float4* xp4 = (const float4*)xp + (b * N1 + nBase) * (DD / 4);
    const float4* yp4 = (const float4*)yp + (b * N2 + mBase) * (DD / 4);
    const float4* __restrict__ W2v = (const float4*)W2;

    // staging per 64-d chunk: xs = 32 rows x 16 f4 (2 f4/thread),
    //                         ys = 16 rows x 16 f4 (1 f4/thread)
    const int xsr = tid >> 3;           // 0..31  xs row
    const int xsc = tid & 7;            // 0..7   xs f4 col (and +8)
    const int ysr = tid >> 4;           // 0..15  ys row
    const int ysc = tid & 15;           // 0..15  ys f4 col

    float4 px0, px1, py0;
    px0 = xp4[xsr * 64 + 0 * 16 + xsc];
    px1 = xp4[xsr * 64 + 0 * 16 + xsc + 8];
    py0 = yp4[ysr * 64 + 0 * 16 + ysc];
    *(float4*)&xs[0][xsr * 68 + xsc * 4]       = px0;
    *(float4*)&xs[0][xsr * 68 + (xsc + 8) * 4] = px1;
    *(float4*)&ys[0][ysr * 68 + ysc * 4]       = py0;
    __syncthreads();

    f2 accA[2] = {};   // lo-half accumulators
    f2 accB[2] = {};   // hi-half accumulators

    for (int kc = 0; kc < 4; ++kc) {
        const int cur = kc & 1;
        const float* __restrict__ xsp = &xs[cur][0];
        const float* __restrict__ ysp = &ys[cur][0];
        if (kc < 3) {   // issue next chunk's global loads; consumed after compute
            px0 = xp4[xsr * 64 + (kc + 1) * 16 + xsc];
            px1 = xp4[xsr * 64 + (kc + 1) * 16 + xsc + 8];
            py0 = yp4[ysr * 64 + (kc + 1) * 16 + ysc];
        }

        #pragma unroll
        for (int c4 = 0; c4 < 16; ++c4) {
            float4 wv = W2v[kc * 16 + c4];   // uniform -> scalar load
            f2 wlo = {wv.x, wv.y};           // raw weights; 0.5 in epilogue
            f2 whi = {wv.z, wv.w};
            float4 yr = *(const float4*)&ysp[tx * 68 + c4 * 4];
            f2 ylo = {yr.x, yr.y};
            f2 yhi = {yr.z, yr.w};
            #pragma unroll
            for (int i = 0; i < 2; ++i) {
                float4 xr = *(const float4*)&xsp[(ty + 16 * i) * 68 + c4 * 4];
                f2 xlo = {xr.x, xr.y};
                f2 xhi = {xr.z, xr.w};
                f2 hlo = xlo + ylo;
                f2 hhi = xhi + yhi;
                f2 ulo = hlo * hlo;
                f2 uhi = hhi * hhi;
                // q = Q(u): erf(h/sqrt2) = h*Q(h^2), Horner deg-6 in u
                f2 qlo = __builtin_elementwise_fma(ulo, (f2)GC13, (f2)GC11);
                f2 qhi = __builtin_elementwise_fma(uhi, (f2)GC13, (f2)GC11);
                qlo = __builtin_elementwise_fma(qlo, ulo, (f2)GC9);
                qhi = __builtin_elementwise_fma(qhi, uhi, (f2)GC9);
                qlo = __builtin_elementwise_fma(qlo, ulo, (f2)GC7);
                qhi = __builtin_elementwise_fma(qhi, uhi, (f2)GC7);
                qlo = __builtin_elementwise_fma(qlo, ulo, (f2)GC5);
                qhi = __builtin_elementwise_fma(qhi, uhi, (f2)GC5);
                qlo = __builtin_elementwise_fma(qlo, ulo, (f2)GC3);
                qhi = __builtin_elementwise_fma(qhi, uhi, (f2)GC3);
                qlo = __builtin_elementwise_fma(qlo, ulo, (f2)GC1);
                qhi = __builtin_elementwise_fma(qhi, uhi, (f2)GC1);
                // gelu = 0.5*(h + u*q); the 0.5 is applied in the epilogue
                f2 slo = __builtin_elementwise_fma(ulo, qlo, hlo);
                f2 shi = __builtin_elementwise_fma(uhi, qhi, hhi);
                accA[i] = __builtin_elementwise_fma(slo, wlo, accA[i]);
                accB[i] = __builtin_elementwise_fma(shi, whi, accB[i]);
            }
        }

        if (kc < 3) {   // drain prefetch into the other buffer; ONE barrier
            const int nxt = cur ^ 1;
            *(float4*)&xs[nxt][xsr * 68 + xsc * 4]       = px0;
            *(float4*)&xs[nxt][xsr * 68 + (xsc + 8) * 4] = px1;
            *(float4*)&ys[nxt][ysr * 68 + ysc * 4]       = py0;
            __syncthreads();
        }
    }

    const float bias2 = b2[0];
    const size_t base = ((size_t)(b * N1 + nBase)) * N2 + mBase;
    #pragma unroll
    for (int i = 0; i < 2; ++i) {
        o[base + (size_t)(ty + 16 * i) * N2 + tx] =
            0.5f * (accA[i].x + accA[i].y + accB[i].x + accB[i].y) + bias2;
    }
}

extern "C" void kernel_launch(void* const* d_in, const int* in_sizes, int n_in,
                              void* d_out, int out_size, void* d_ws, size_t ws_size,
                              hipStream_t stream)
{
    const float* x  = (const float*)d_in[0];
    const float* y  = (const float*)d_in[1];
    const float* W1 = (const float*)d_in[2];
    const float* b1 = (const float*)d_in[3];
    const float* W2 = (const float*)d_in[4];
    const float* b2 = (const float*)d_in[5];
    float* o  = (float*)d_out;
    float* xp = (float*)d_ws;                 // 2048*256 floats = 2 MB
    float* yp = xp + (BB * N1) * DD;          // next 2 MB

    dim3 g1(64, 4, 2);               // (M/32, N/64, which) = 512 blocks
    proj_kernel<<<g1, 256, 0, stream>>>(x, y, W1, b1, xp, yp);

    dim3 g2(N2 / 16, N1 / 32, BB);   // 32 x 16 x 4 = 2048 blocks
    cross_kernel<<<g2, 256, 0, stream>>>(xp, yp, W2, b2, o);
}

// Round 10
// 134.352 us; speedup vs baseline: 2.3261x; 2.3261x over previous
//
#include <hip/hip_runtime.h>

#define DD 256   // feature dim
#define N1 512
#define N2 512
#define BB 4

// Packed fp32: gfx950 (gfx90a+) PackedFP32Ops; the compiler selects
// v_pk_{add,mul,fma}_f32 from <2 x float> vector IR.
typedef float f2 __attribute__((ext_vector_type(2)));

// ---------------------------------------------------------------------------
// Kernel 1: projection GEMMs. R2 version verbatim: 32x64 tile / 256 threads /
// 2x4 register blocking (packed), K-chunks of 32, register-prefetch double
// buffering, 512 blocks = 2/CU. proj ~15-25 us; R3 proved its internal
// structure doesn't move the total. Leave it alone.
// ---------------------------------------------------------------------------
__global__ __launch_bounds__(256) void proj_kernel(
    const float* __restrict__ x, const float* __restrict__ y,
    const float* __restrict__ W1, const float* __restrict__ b1,
    float* __restrict__ xp, float* __restrict__ yp)
{
    const int which = blockIdx.z;
    const float* __restrict__ A  = which ? y : x;
    const float* __restrict__ Bw = W1 + which * DD * DD;
    float* __restrict__ outp = which ? yp : xp;

    __shared__ float As[32 * 36];   // As[k][m] (transposed), stride 36
    __shared__ float Bs[32 * 68];   // Bs[k][n], stride 68

    const int tid = threadIdx.x;
    const int tx = tid & 15, ty = tid >> 4;
    const int mBase = blockIdx.x * 32;
    const int nBase = blockIdx.y * 64;

    const float4* A4 = (const float4*)A;
    const float4* B4 = (const float4*)Bw;

    const int ar = tid >> 3;       // 0..31  A row (m)
    const int ac = tid & 7;        // 0..7   A float4 col (k/4)
    const int br = tid >> 4;       // 0..15  B k-row (and +16)
    const int bc = tid & 15;       // 0..15  B float4 col (n/4)

    float4 pa, pb0, pb1;
    pa  = A4[(mBase + ar) * 64 + 0 * 8 + ac];
    pb0 = B4[(0 * 32 + br) * 64 + (nBase >> 2) + bc];
    pb1 = B4[(0 * 32 + br + 16) * 64 + (nBase >> 2) + bc];

    // acc[i] split into lo/hi f2 halves of the 4-wide n block -> v_pk_fma
    f2 accl[2] = {}, acch[2] = {};

    for (int kc = 0; kc < 8; ++kc) {
        __syncthreads();
        {
            float av[4] = {pa.x, pa.y, pa.z, pa.w};
            #pragma unroll
            for (int q = 0; q < 4; ++q) As[(ac * 4 + q) * 36 + ar] = av[q];
            *(float4*)&Bs[br * 68 + bc * 4] = pb0;
            *(float4*)&Bs[(br + 16) * 68 + bc * 4] = pb1;
        }
        __syncthreads();
        if (kc < 7) {
            pa  = A4[(mBase + ar) * 64 + (kc + 1) * 8 + ac];
            pb0 = B4[((kc + 1) * 32 + br) * 64 + (nBase >> 2) + bc];
            pb1 = B4[((kc + 1) * 32 + br + 16) * 64 + (nBase >> 2) + bc];
        }
        #pragma unroll
        for (int k = 0; k < 32; ++k) {
            f2 a = *(const f2*)&As[k * 36 + ty * 2];
            float4 b = *(const float4*)&Bs[k * 68 + tx * 4];
            f2 blo = {b.x, b.y};
            f2 bhi = {b.z, b.w};
            f2 a0 = {a.x, a.x};     // splat -> op_sel, free in VOP3P
            f2 a1 = {a.y, a.y};
            accl[0] = __builtin_elementwise_fma(a0, blo, accl[0]);
            acch[0] = __builtin_elementwise_fma(a0, bhi, acch[0]);
            accl[1] = __builtin_elementwise_fma(a1, blo, accl[1]);
            acch[1] = __builtin_elementwise_fma(a1, bhi, acch[1]);
        }
    }

    float4 bias = make_float4(0.f, 0.f, 0.f, 0.f);
    if (which == 0) bias = *((const float4*)b1 + (nBase >> 2) + tx);
    #pragma unroll
    for (int i = 0; i < 2; ++i) {
        float4 o;
        o.x = accl[i].x + bias.x;
        o.y = accl[i].y + bias.y;
        o.z = acch[i].x + bias.z;
        o.w = acch[i].y + bias.w;
        ((float4*)outp)[(mBase + ty * 2 + i) * (DD / 4) + (nBase >> 2) + tx] = o;
    }
}

// ---------------------------------------------------------------------------
// Kernel 2: o[b,n,m] = sum_d gelu(xp[b,n,d] + yp[b,m,d]) * W2[d] + b2
// R8 skeleton (61 us proven) with K_CHUNK=128: 2 chunks instead of 4 ->
// 4 barriers/block instead of 8. SINGLE-buffer LDS only -- runtime-indexed
// double-buffering is condemned (R1 & R9 both: VGPR/SGPR jump + 1.2 GB
// scratch traffic + 4x slowdown). LDS 24.75 KB -> 6 blocks/CU = 24 waves/CU
// (was 32); trade ~25% occupancy for half the barrier-drain sections.
//
// Gelu: trans-free deg-13 odd Chebyshev erf poly (R8-proven, absmax
// unchanged). gelu = 0.5*(h + u*Q(u)), u=h^2; the 0.5 applied ONCE in the
// epilogue (R9's safe micro-win, unbundled from the dbuf disaster).
// ---------------------------------------------------------------------------
#define GC1  0.79687960f
#define GC3  (-0.13053245f)
#define GC5  0.018104800f
#define GC7  (-0.0017319756f)
#define GC9  1.05671e-4f
#define GC11 (-3.64829e-6f)
#define GC13 5.37117e-8f

__global__ __launch_bounds__(256, 4) void cross_kernel(
    const float* __restrict__ xp, const float* __restrict__ yp,
    const float* __restrict__ W2, const float* __restrict__ b2,
    float* __restrict__ o)
{
    __shared__ float xs[32 * 132];   // 32 n-rows x 128-d chunk, stride 132
    __shared__ float ys[16 * 132];   // 16 m-rows x 128-d chunk, stride 132

    const int tid   = threadIdx.x;
    const int b     = blockIdx.z;
    const int mBase = blockIdx.x * 16;
    const int nBase = blockIdx.y * 32;
    const int tx = tid & 15;       // m col (single)
    const int ty = tid >> 4;       // n rows ty, ty+16

    const float4* xp4 = (const float4*)xp + (b * N1 + nBase) * (DD / 4);
    const float4* yp4 = (const float4*)yp + (b * N2 + mBase) * (DD / 4);
    const float4* __restrict__ W2v = (const float4*)W2;

    // staging per 128-d chunk: xs = 32 rows x 32 f4 (4 f4/thread),
    //                          ys = 16 rows x 32 f4 (2 f4/thread)
    const int xsr = tid >> 3;           // 0..31  xs row
    const int xsc = tid & 7;            // 0..7   xs f4 col (and +8,+16,+24)
    const int ysr = tid >> 4;           // 0..15  ys row
    const int ysc = tid & 15;           // 0..15  ys f4 col (and +16)

    float4 px[4], py[2];
    #pragma unroll
    for (int j = 0; j < 4; ++j) px[j] = xp4[xsr * 64 + xsc + 8 * j];
    #pragma unroll
    for (int j = 0; j < 2; ++j) py[j] = yp4[ysr * 64 + ysc + 16 * j];

    f2 accA[2] = {};   // lo-half accumulators
    f2 accB[2] = {};   // hi-half accumulators

    for (int kc = 0; kc < 2; ++kc) {
        __syncthreads();
        #pragma unroll
        for (int j = 0; j < 4; ++j)
            *(float4*)&xs[xsr * 132 + (xsc + 8 * j) * 4] = px[j];
        #pragma unroll
        for (int j = 0; j < 2; ++j)
            *(float4*)&ys[ysr * 132 + (ysc + 16 * j) * 4] = py[j];
        __syncthreads();
        if (kc < 1) {
            #pragma unroll
            for (int j = 0; j < 4; ++j) px[j] = xp4[xsr * 64 + 32 + xsc + 8 * j];
            #pragma unroll
            for (int j = 0; j < 2; ++j) py[j] = yp4[ysr * 64 + 32 + ysc + 16 * j];
        }

        #pragma unroll
        for (int c4 = 0; c4 < 32; ++c4) {
            float4 wv = W2v[kc * 32 + c4];   // uniform -> scalar load
            f2 wlo = {wv.x, wv.y};           // raw weights; 0.5 in epilogue
            f2 whi = {wv.z, wv.w};
            float4 yr = *(const float4*)&ys[tx * 132 + c4 * 4];
            f2 ylo = {yr.x, yr.y};
            f2 yhi = {yr.z, yr.w};
            #pragma unroll
            for (int i = 0; i < 2; ++i) {
                float4 xr = *(const float4*)&xs[(ty + 16 * i) * 132 + c4 * 4];
                f2 xlo = {xr.x, xr.y};
                f2 xhi = {xr.z, xr.w};
                f2 hlo = xlo + ylo;
                f2 hhi = xhi + yhi;
                f2 ulo = hlo * hlo;
                f2 uhi = hhi * hhi;
                // q = Q(u): erf(h/sqrt2) = h*Q(h^2), Horner deg-6 in u
                f2 qlo = __builtin_elementwise_fma(ulo, (f2)GC13, (f2)GC11);
                f2 qhi = __builtin_elementwise_fma(uhi, (f2)GC13, (f2)GC11);
                qlo = __builtin_elementwise_fma(qlo, ulo, (f2)GC9);
                qhi = __builtin_elementwise_fma(qhi, uhi, (f2)GC9);
                qlo = __builtin_elementwise_fma(qlo, ulo, (f2)GC7);
                qhi = __builtin_elementwise_fma(qhi, uhi, (f2)GC7);
                qlo = __builtin_elementwise_fma(qlo, ulo, (f2)GC5);
                qhi = __builtin_elementwise_fma(qhi, uhi, (f2)GC5);
                qlo = __builtin_elementwise_fma(qlo, ulo, (f2)GC3);
                qhi = __builtin_elementwise_fma(qhi, uhi, (f2)GC3);
                qlo = __builtin_elementwise_fma(qlo, ulo, (f2)GC1);
                qhi = __builtin_elementwise_fma(qhi, uhi, (f2)GC1);
                // gelu = 0.5*(h + u*q); the 0.5 is applied in the epilogue
                f2 slo = __builtin_elementwise_fma(ulo, qlo, hlo);
                f2 shi = __builtin_elementwise_fma(uhi, qhi, hhi);
                accA[i] = __builtin_elementwise_fma(slo, wlo, accA[i]);
                accB[i] = __builtin_elementwise_fma(shi, whi, accB[i]);
            }
        }
    }

    const float bias2 = b2[0];
    const size_t base = ((size_t)(b * N1 + nBase)) * N2 + mBase;
    #pragma unroll
    for (int i = 0; i < 2; ++i) {
        o[base + (size_t)(ty + 16 * i) * N2 + tx] =
            0.5f * (accA[i].x + accA[i].y + accB[i].x + accB[i].y) + bias2;
    }
}

extern "C" void kernel_launch(void* const* d_in, const int* in_sizes, int n_in,
                              void* d_out, int out_size, void* d_ws, size_t ws_size,
                              hipStream_t stream)
{
    const float* x  = (const float*)d_in[0];
    const float* y  = (const float*)d_in[1];
    const float* W1 = (const float*)d_in[2];
    const float* b1 = (const float*)d_in[3];
    const float* W2 = (const float*)d_in[4];
    const float* b2 = (const float*)d_in[5];
    float* o  = (float*)d_out;
    float* xp = (float*)d_ws;                 // 2048*256 floats = 2 MB
    float* yp = xp + (BB * N1) * DD;          // next 2 MB

    dim3 g1(64, 4, 2);               // (M/32, N/64, which) = 512 blocks
    proj_kernel<<<g1, 256, 0, stream>>>(x, y, W1, b1, xp, yp);

    dim3 g2(N2 / 16, N1 / 32, BB);   // 32 x 16 x 4 = 2048 blocks
    cross_kernel<<<g2, 256, 0, stream>>>(xp, yp, W2, b2, o);
}

// Round 11
// 123.836 us; speedup vs baseline: 2.5236x; 1.0849x over previous
//
#include <hip/hip_runtime.h>

#define DD 256   // feature dim
#define N1 512
#define N2 512
#define BB 4

// Packed fp32: gfx950 (gfx90a+) PackedFP32Ops; the compiler selects
// v_pk_{add,mul,fma}_f32 from <2 x float> vector IR.
typedef float f2 __attribute__((ext_vector_type(2)));

// ---------------------------------------------------------------------------
// Kernel 1: projection GEMMs. R2 version verbatim: 32x64 tile / 256 threads /
// 2x4 register blocking (packed), K-chunks of 32, register-prefetch double
// buffering, 512 blocks = 2/CU. Proven; leave alone.
// ---------------------------------------------------------------------------
__global__ __launch_bounds__(256) void proj_kernel(
    const float* __restrict__ x, const float* __restrict__ y,
    const float* __restrict__ W1, const float* __restrict__ b1,
    float* __restrict__ xp, float* __restrict__ yp)
{
    const int which = blockIdx.z;
    const float* __restrict__ A  = which ? y : x;
    const float* __restrict__ Bw = W1 + which * DD * DD;
    float* __restrict__ outp = which ? yp : xp;

    __shared__ float As[32 * 36];   // As[k][m] (transposed), stride 36
    __shared__ float Bs[32 * 68];   // Bs[k][n], stride 68

    const int tid = threadIdx.x;
    const int tx = tid & 15, ty = tid >> 4;
    const int mBase = blockIdx.x * 32;
    const int nBase = blockIdx.y * 64;

    const float4* A4 = (const float4*)A;
    const float4* B4 = (const float4*)Bw;

    const int ar = tid >> 3;       // 0..31  A row (m)
    const int ac = tid & 7;        // 0..7   A float4 col (k/4)
    const int br = tid >> 4;       // 0..15  B k-row (and +16)
    const int bc = tid & 15;       // 0..15  B float4 col (n/4)

    float4 pa, pb0, pb1;
    pa  = A4[(mBase + ar) * 64 + 0 * 8 + ac];
    pb0 = B4[(0 * 32 + br) * 64 + (nBase >> 2) + bc];
    pb1 = B4[(0 * 32 + br + 16) * 64 + (nBase >> 2) + bc];

    // acc[i] split into lo/hi f2 halves of the 4-wide n block -> v_pk_fma
    f2 accl[2] = {}, acch[2] = {};

    for (int kc = 0; kc < 8; ++kc) {
        __syncthreads();
        {
            float av[4] = {pa.x, pa.y, pa.z, pa.w};
            #pragma unroll
            for (int q = 0; q < 4; ++q) As[(ac * 4 + q) * 36 + ar] = av[q];
            *(float4*)&Bs[br * 68 + bc * 4] = pb0;
            *(float4*)&Bs[(br + 16) * 68 + bc * 4] = pb1;
        }
        __syncthreads();
        if (kc < 7) {
            pa  = A4[(mBase + ar) * 64 + (kc + 1) * 8 + ac];
            pb0 = B4[((kc + 1) * 32 + br) * 64 + (nBase >> 2) + bc];
            pb1 = B4[((kc + 1) * 32 + br + 16) * 64 + (nBase >> 2) + bc];
        }
        #pragma unroll
        for (int k = 0; k < 32; ++k) {
            f2 a = *(const f2*)&As[k * 36 + ty * 2];
            float4 b = *(const float4*)&Bs[k * 68 + tx * 4];
            f2 blo = {b.x, b.y};
            f2 bhi = {b.z, b.w};
            f2 a0 = {a.x, a.x};     // splat -> op_sel, free in VOP3P
            f2 a1 = {a.y, a.y};
            accl[0] = __builtin_elementwise_fma(a0, blo, accl[0]);
            acch[0] = __builtin_elementwise_fma(a0, bhi, acch[0]);
            accl[1] = __builtin_elementwise_fma(a1, blo, accl[1]);
            acch[1] = __builtin_elementwise_fma(a1, bhi, acch[1]);
        }
    }

    float4 bias = make_float4(0.f, 0.f, 0.f, 0.f);
    if (which == 0) bias = *((const float4*)b1 + (nBase >> 2) + tx);
    #pragma unroll
    for (int i = 0; i < 2; ++i) {
        float4 o;
        o.x = accl[i].x + bias.x;
        o.y = accl[i].y + bias.y;
        o.z = acch[i].x + bias.z;
        o.w = acch[i].y + bias.w;
        ((float4*)outp)[(mBase + ty * 2 + i) * (DD / 4) + (nBase >> 2) + tx] = o;
    }
}

// ---------------------------------------------------------------------------
// Kernel 2: o[b,n,m] = sum_d gelu(xp[b,n,d] + yp[b,m,d]) * W2[d] + b2
// R11: R8 kernel (61 us proven) + STATIC double-buffer. Both prior dbuf
// attempts (R1, R9) used runtime-indexed buffer selection (xs[cur]) and hit
// the rule-#20 scratch catastrophe (VGPR/SGPR jump, ~1.2 GB phantom traffic).
// This version has ZERO runtime selects and ZERO pointer variables: the
// 4-chunk loop is written out straight-line with separately NAMED buffers
// (xsA/xsB, ysA/ysB) and text macros. 5 barriers instead of 8, and the
// ds_write staging overlaps the barrier-free gap after compute.
// Hazard audit: every STAGE_WRITE to buffer P is after a barrier that
// post-dates all threads' COMPUTE on P.
// TRIPWIRE: FETCH>15MB or VGPR>=64 => scratch => revert to R8, declare.
//
// Gelu: trans-free deg-13 odd Chebyshev erf poly (R8-proven, absmax
// unchanged 0.00390625); 0.5 folded once into the epilogue.
// K_CHUNK=64 (R10 proved 128 regresses). LDS 26112 B -> 6 blocks/CU.
// ---------------------------------------------------------------------------
#define GC1  0.79687960f
#define GC3  (-0.13053245f)
#define GC5  0.018104800f
#define GC7  (-0.0017319756f)
#define GC9  1.05671e-4f
#define GC11 (-3.64829e-6f)
#define GC13 5.37117e-8f

__global__ __launch_bounds__(256, 4) void cross_kernel(
    const float* __restrict__ xp, const float* __restrict__ yp,
    const float* __restrict__ W2, const float* __restrict__ b2,
    float* __restrict__ o)
{
    __shared__ float xsA[32 * 68];
    __shared__ float xsB[32 * 68];
    __shared__ float ysA[16 * 68];
    __shared__ float ysB[16 * 68];

    const int tid   = threadIdx.x;
    const int b     = blockIdx.z;
    const int mBase = blockIdx.x * 16;
    const int nBase = blockIdx.y * 32;
    const int tx = tid & 15;       // m col (single)
    const int ty = tid >> 4;       // n rows ty, ty+16

    const float4* xp4 = (const float4*)xp + (b * N1 + nBase) * (DD / 4);
    const float4* yp4 = (const float4*)yp + (b * N2 + mBase) * (DD / 4);
    const float4* __restrict__ W2v = (const float4*)W2;

    // staging per 64-d chunk: xs = 32 rows x 16 f4 (2 f4/thread),
    //                         ys = 16 rows x 16 f4 (1 f4/thread)
    const int xsr = tid >> 3;           // 0..31  xs row
    const int xsc = tid & 7;            // 0..7   xs f4 col (and +8)
    const int ysr = tid >> 4;           // 0..15  ys row
    const int ysc = tid & 15;           // 0..15  ys f4 col

    float4 px0, px1, py0;
    f2 accA[2] = {};   // lo-half accumulators
    f2 accB[2] = {};   // hi-half accumulators

#define STAGE_LOAD(CH)                                      \
    px0 = xp4[xsr * 64 + (CH) * 16 + xsc];                  \
    px1 = xp4[xsr * 64 + (CH) * 16 + xsc + 8];              \
    py0 = yp4[ysr * 64 + (CH) * 16 + ysc];

#define STAGE_WRITE(XS, YS)                                 \
    *(float4*)&XS[xsr * 68 + xsc * 4]       = px0;          \
    *(float4*)&XS[xsr * 68 + (xsc + 8) * 4] = px1;          \
    *(float4*)&YS[ysr * 68 + ysc * 4]       = py0;

#define COMPUTE(XS, YS, KC)                                                    \
    _Pragma("unroll")                                                          \
    for (int c4 = 0; c4 < 16; ++c4) {                                          \
        float4 wv = W2v[(KC) * 16 + c4];                                       \
        f2 wlo = {wv.x, wv.y};                                                 \
        f2 whi = {wv.z, wv.w};                                                 \
        float4 yr = *(const float4*)&YS[tx * 68 + c4 * 4];                     \
        f2 ylo = {yr.x, yr.y};                                                 \
        f2 yhi = {yr.z, yr.w};                                                 \
        _Pragma("unroll")                                                      \
        for (int i = 0; i < 2; ++i) {                                          \
            float4 xr = *(const float4*)&XS[(ty + 16 * i) * 68 + c4 * 4];      \
            f2 xlo = {xr.x, xr.y};                                             \
            f2 xhi = {xr.z, xr.w};                                             \
            f2 hlo = xlo + ylo;                                                \
            f2 hhi = xhi + yhi;                                                \
            f2 ulo = hlo * hlo;                                                \
            f2 uhi = hhi * hhi;                                                \
            f2 qlo = __builtin_elementwise_fma(ulo, (f2)GC13, (f2)GC11);       \
            f2 qhi = __builtin_elementwise_fma(uhi, (f2)GC13, (f2)GC11);       \
            qlo = __builtin_elementwise_fma(qlo, ulo, (f2)GC9);                \
            qhi = __builtin_elementwise_fma(qhi, uhi, (f2)GC9);                \
            qlo = __builtin_elementwise_fma(qlo, ulo, (f2)GC7);                \
            qhi = __builtin_elementwise_fma(qhi, uhi, (f2)GC7);                \
            qlo = __builtin_elementwise_fma(qlo, ulo, (f2)GC5);                \
            qhi = __builtin_elementwise_fma(qhi, uhi, (f2)GC5);                \
            qlo = __builtin_elementwise_fma(qlo, ulo, (f2)GC3);                \
            qhi = __builtin_elementwise_fma(qhi, uhi, (f2)GC3);                \
            qlo = __builtin_elementwise_fma(qlo, ulo, (f2)GC1);                \
            qhi = __builtin_elementwise_fma(qhi, uhi, (f2)GC1);                \
            f2 slo = __builtin_elementwise_fma(ulo, qlo, hlo);                 \
            f2 shi = __builtin_elementwise_fma(uhi, qhi, hhi);                 \
            accA[i] = __builtin_elementwise_fma(slo, wlo, accA[i]);            \
            accB[i] = __builtin_elementwise_fma(shi, whi, accB[i]);            \
        }                                                                      \
    }

    STAGE_LOAD(0)
    STAGE_WRITE(xsA, ysA)
    __syncthreads();                    // B0: bufA(chunk0) ready

    STAGE_LOAD(1)                       // global latency hides under compute
    COMPUTE(xsA, ysA, 0)
    STAGE_WRITE(xsB, ysB)
    __syncthreads();                    // B1: bufB(chunk1) ready, bufA free

    STAGE_LOAD(2)
    COMPUTE(xsB, ysB, 1)
    STAGE_WRITE(xsA, ysA)
    __syncthreads();                    // B2: bufA(chunk2) ready, bufB free

    STAGE_LOAD(3)
    COMPUTE(xsA, ysA, 2)
    STAGE_WRITE(xsB, ysB)
    __syncthreads();                    // B3: bufB(chunk3) ready

    COMPUTE(xsB, ysB, 3)

#undef STAGE_LOAD
#undef STAGE_WRITE
#undef COMPUTE

    const float bias2 = b2[0];
    const size_t base = ((size_t)(b * N1 + nBase)) * N2 + mBase;
    #pragma unroll
    for (int i = 0; i < 2; ++i) {
        o[base + (size_t)(ty + 16 * i) * N2 + tx] =
            0.5f * (accA[i].x + accA[i].y + accB[i].x + accB[i].y) + bias2;
    }
}

extern "C" void kernel_launch(void* const* d_in, const int* in_sizes, int n_in,
                              void* d_out, int out_size, void* d_ws, size_t ws_size,
                              hipStream_t stream)
{
    const float* x  = (const float*)d_in[0];
    const float* y  = (const float*)d_in[1];
    const float* W1 = (const float*)d_in[2];
    const float* b1 = (const float*)d_in[3];
    const float* W2 = (const float*)d_in[4];
    const float* b2 = (const float*)d_in[5];
    float* o  = (float*)d_out;
    float* xp = (float*)d_ws;                 // 2048*256 floats = 2 MB
    float* yp = xp + (BB * N1) * DD;          // next 2 MB

    dim3 g1(64, 4, 2);               // (M/32, N/64, which) = 512 blocks
    proj_kernel<<<g1, 256, 0, stream>>>(x, y, W1, b1, xp, yp);

    dim3 g2(N2 / 16, N1 / 32, BB);   // 32 x 16 x 4 = 2048 blocks
    cross_kernel<<<g2, 256, 0, stream>>>(xp, yp, W2, b2, o);
}